// Round 6
// baseline (446.927 us; speedup 1.0000x reference)
//
#include <hip/hip_runtime.h>
#include <hip/hip_bf16.h>
#include <hip/hip_cooperative_groups.h>

namespace cg = cooperative_groups;

typedef __attribute__((ext_vector_type(4))) float floatx4;
typedef __bf16 bf16x8 __attribute__((ext_vector_type(8)));
typedef unsigned int u32;
typedef unsigned short u16;

typedef __attribute__((address_space(1))) const u32 g_u32;
typedef __attribute__((address_space(3))) u32 l_u32;

__device__ __forceinline__ u16 f32_to_bf16(float f) {
    union { float f; u32 u; } x{f};
    u32 u = x.u;
    u32 r = (u + 0x7fffu + ((u >> 16) & 1u)) >> 16;
    return (u16)r;
}

// ============================================================================
// 8-phase 256x256 GEMM schedule (T1+T2+T3/T4+T5). Verified R2-R5: 0 bank
// conflicts, T(block) ~= 38.8us @K=1024, linear in iters (pv R5).
// DO NOT EDIT barrier/vmcnt placement. ITERS runtime >=1; TMAX clamps tail.
// ============================================================================

__device__ __forceinline__ void stage_half_sw(const u16* gbase, int ld, u16* lds_half, int tid) {
    int lane = tid & 63;
    int rsub = lane >> 3;                        // 0..7 row within 8-row slab
    int colsw = ((lane & 7) ^ rsub) << 3;        // swizzled source column (elems)
#pragma unroll
    for (int j = 0; j < 2; ++j) {
        int q = (tid >> 6) * 2 + j;              // 8-row slab index 0..15
        int row = q * 8 + rsub;
        const u16* g = gbase + (long)row * ld + colsw;
        u16* l = lds_half + q * 512 + lane * 8;  // linear: wave base + lane*16B
        __builtin_amdgcn_global_load_lds((g_u32*)g, (l_u32*)l, 16, 0, 0);
    }
}

#define EIGHT_PHASE_LOOP(Ab, Bb, lda, ldb, ITERS, TMAX)                                \
    stage_half_sw(Bb,                  ldb, &Bs[0][0],        tid);                    \
    stage_half_sw(Bb + 128 * (ldb),    ldb, &Bs[0][128 * 64], tid);                    \
    stage_half_sw(Ab,                  lda, &As[0][0],        tid);                    \
    stage_half_sw(Ab + 128 * (lda),    lda, &As[0][128 * 64], tid);                    \
    stage_half_sw(Bb + 64,             ldb, &Bs[1][0],        tid);                    \
    stage_half_sw(Bb + 64 + 128 * (ldb), ldb, &Bs[1][128 * 64], tid);                  \
    asm volatile("s_waitcnt vmcnt(4)" ::: "memory");                                   \
    __builtin_amdgcn_sched_barrier(0);                                                 \
    __builtin_amdgcn_s_barrier();                                                      \
    for (int i = 0; i < (ITERS); ++i) {                                                \
        int t1  = 2 * i + 1;                                                           \
        int tn  = (2 * i + 2 <= (TMAX)) ? 2 * i + 2 : (TMAX);                          \
        int tn1 = (2 * i + 3 <= (TMAX)) ? 2 * i + 3 : (TMAX);                          \
        const u16* gA1 = Ab + t1 * 64;                                                 \
        const u16* gB2 = Bb + tn * 64;                                                 \
        const u16* gA2 = Ab + tn * 64;                                                 \
        const u16* gB3 = Bb + tn1 * 64;                                                \
        bf16x8 bq0[4], bq1[4];                                                         \
        _Pragma("unroll")                                                              \
        for (int half = 0; half < 2; ++half) {                                         \
            _Pragma("unroll")                                                          \
            for (int p = 0; p < 4; ++p) {                                              \
                if (p == 0) {                                                          \
                    _Pragma("unroll")                                                  \
                    for (int ni = 0; ni < 4; ++ni) {                                   \
                        bq0[ni] = *(const bf16x8*)&Bs[half][brow + ni * 1024 + sl0];   \
                        bq1[ni] = *(const bf16x8*)&Bs[half][brow + ni * 1024 + sl1];   \
                    }                                                                  \
                }                                                                      \
                bf16x8 a00 = *(const bf16x8*)&As[half][arow + (2 * p)     * 1024 + sl0]; \
                bf16x8 a01 = *(const bf16x8*)&As[half][arow + (2 * p)     * 1024 + sl1]; \
                bf16x8 a10 = *(const bf16x8*)&As[half][arow + (2 * p + 1) * 1024 + sl0]; \
                bf16x8 a11 = *(const bf16x8*)&As[half][arow + (2 * p + 1) * 1024 + sl1]; \
                int ph = half * 4 + p;                                                 \
                switch (ph) {                                                          \
                    case 0: stage_half_sw(gA1,              lda, &As[1][0],        tid); break; \
                    case 1: stage_half_sw(gA1 + 128 * (lda), lda, &As[1][128 * 64], tid); break; \
                    case 2: stage_half_sw(gB2,              ldb, &Bs[0][0],        tid); break; \
                    case 3: stage_half_sw(gB2 + 128 * (ldb), ldb, &Bs[0][128 * 64], tid); break; \
                    case 4: stage_half_sw(gA2,              lda, &As[0][0],        tid); break; \
                    case 5: stage_half_sw(gA2 + 128 * (lda), lda, &As[0][128 * 64], tid); break; \
                    case 6: stage_half_sw(gB3,              ldb, &Bs[1][0],        tid); break; \
                    case 7: stage_half_sw(gB3 + 128 * (ldb), ldb, &Bs[1][128 * 64], tid); break; \
                }                                                                      \
                __builtin_amdgcn_s_barrier();                                          \
                __builtin_amdgcn_s_setprio(1);                                         \
                int m0 = 2 * p;                                                        \
                _Pragma("unroll")                                                      \
                for (int ni = 0; ni < 4; ++ni) {                                       \
                    acc[m0][ni]     = __builtin_amdgcn_mfma_f32_16x16x32_bf16(a00, bq0[ni], acc[m0][ni],     0, 0, 0); \
                    acc[m0][ni]     = __builtin_amdgcn_mfma_f32_16x16x32_bf16(a01, bq1[ni], acc[m0][ni],     0, 0, 0); \
                    acc[m0 + 1][ni] = __builtin_amdgcn_mfma_f32_16x16x32_bf16(a10, bq0[ni], acc[m0 + 1][ni], 0, 0, 0); \
                    acc[m0 + 1][ni] = __builtin_amdgcn_mfma_f32_16x16x32_bf16(a11, bq1[ni], acc[m0 + 1][ni], 0, 0, 0); \
                }                                                                      \
                __builtin_amdgcn_s_setprio(0);                                         \
                if (p == 3) {                                                          \
                    asm volatile("s_waitcnt vmcnt(4)" ::: "memory");                   \
                    __builtin_amdgcn_sched_barrier(0);                                 \
                }                                                                      \
                __builtin_amdgcn_s_barrier();                                          \
            }                                                                          \
        }                                                                              \
    }                                                                                  \
    asm volatile("s_waitcnt vmcnt(0)" ::: "memory");                                   \
    __builtin_amdgcn_sched_barrier(0);

typedef u16 lds_t[256 * 64];

// ---------------- QKV unit (R5-frozen body) ----------------
__device__ __forceinline__ void qkv_unit(int mt, int nt,
    const u16* __restrict__ A, const u16* __restrict__ Bw,
    u16* __restrict__ QKi, u16* __restrict__ Vt, lds_t* As, lds_t* Bs, int tid)
{
    int lane = tid & 63, wv = tid >> 6;
    int wr = wv >> 2, wc = wv & 3;
    int lrow = lane & 15, quad = lane >> 4;
    int sw = lrow & 7;

    const u16* Ab = A + (long)mt * 256 * 1024;
    const u16* Bb = Bw + (long)nt * 256 * 1024;

    floatx4 acc[8][4] = {};
    const int arow = (wr * 128 + lrow) * 64;
    const int brow = (wc * 64 + lrow) * 64;
    const int sl0 = (quad ^ sw) * 8;
    const int sl1 = ((4 + quad) ^ sw) * 8;

    EIGHT_PHASE_LOOP(Ab, Bb, 1024, 1024, 8, 15)

    if (nt < 8) {
        long crow0 = (long)mt * 256 + wr * 128 + quad * 4;
        int  ccol0 = nt * 256 + wc * 64 + lrow;
#pragma unroll
        for (int mi = 0; mi < 8; ++mi) {
#pragma unroll
            for (int r = 0; r < 4; ++r) {
                long row = crow0 + mi * 16 + r;
#pragma unroll
                for (int ni = 0; ni < 4; ++ni)
                    QKi[row * 2048 + ccol0 + ni * 16] = f32_to_bf16(acc[mi][ni][r]);
            }
        }
    } else {
        int dv0   = (nt - 8) * 256 + wc * 64 + lrow;
        long tok0 = (long)mt * 256 + wr * 128 + quad * 4;
#pragma unroll
        for (int mi = 0; mi < 8; ++mi) {
#pragma unroll
            for (int ni = 0; ni < 4; ++ni) {
                ushort4 o;
                o.x = f32_to_bf16(acc[mi][ni][0]);
                o.y = f32_to_bf16(acc[mi][ni][1]);
                o.z = f32_to_bf16(acc[mi][ni][2]);
                o.w = f32_to_bf16(acc[mi][ni][3]);
                *(ushort4*)(Vt + (long)(dv0 + ni * 16) * 16384 + tok0 + mi * 16) = o;
            }
        }
    }
}

// ---------------- S unit (R4/R5-frozen body + release post) ----------------
__device__ __forceinline__ void s_unit(int b, int mt, int nt,
    const u16* __restrict__ QKi, u16* __restrict__ P, float* __restrict__ lsum,
    int* __restrict__ srow, lds_t* As, lds_t* Bs, int tid)
{
    int lane = tid & 63, wv = tid >> 6;
    int wr = wv >> 2, wc = wv & 3;
    int lrow = lane & 15, quad = lane >> 4;
    int sw = lrow & 7;

    const u16* Qb = QKi + (long)b * 2048 * 2048 + (long)mt * 256 * 2048;
    const u16* Kb = QKi + (long)b * 2048 * 2048 + (long)nt * 256 * 2048 + 1024;
    u16* Pb = P + (long)b * 2048 * 2048;
    float* ls = lsum + b * 2048;

    floatx4 acc[8][4] = {};
    const int arow = (wr * 128 + lrow) * 64;
    const int brow = (wc * 64 + lrow) * 64;
    const int sl0 = (quad ^ sw) * 8;
    const int sl1 = ((4 + quad) ^ sw) * 8;

    EIGHT_PHASE_LOOP(Qb, Kb, 2048, 2048, 8, 15)

    int crow0 = mt * 256 + wr * 128 + quad * 4;
    int ccol0 = nt * 256 + wc * 64 + lrow;
#pragma unroll
    for (int mi = 0; mi < 8; ++mi) {
#pragma unroll
        for (int r = 0; r < 4; ++r) {
            int row = crow0 + mi * 16 + r;
            float rs = 0.f;
#pragma unroll
            for (int ni = 0; ni < 4; ++ni) {
                int col = ccol0 + ni * 16;
                float v = acc[mi][ni][r] * 0.03125f;
                float e = (col > row) ? 0.f : __expf(v);
                Pb[(long)row * 2048 + col] = f32_to_bf16(e);
                rs += e;
            }
            rs += __shfl_xor(rs, 1, 16);
            rs += __shfl_xor(rs, 2, 16);
            rs += __shfl_xor(rs, 4, 16);
            rs += __shfl_xor(rs, 8, 16);
            if (lrow == 0) atomicAdd(&ls[row], rs);
        }
    }
    // Release-post row completion: all block stores drained by syncthreads,
    // tid0 fences (wbl2 device scope) then bumps the row counter.
    __syncthreads();
    if (tid == 0) {
        __builtin_amdgcn_fence(__ATOMIC_RELEASE, "agent");
        __hip_atomic_fetch_add(&srow[b * 8 + mt], 1, __ATOMIC_RELAXED, __HIP_MEMORY_SCOPE_AGENT);
    }
}

// ---------------- PV unit (R5-frozen body + acquire spin) ----------------
__device__ __forceinline__ void pv_unit(int b, int mt, int nt,
    const u16* __restrict__ P, const u16* __restrict__ Vt, float* __restrict__ O,
    const float* __restrict__ lsum, int* __restrict__ srow, lds_t* As, lds_t* Bs, int tid)
{
    if (tid == 0) {
        while (__hip_atomic_load(&srow[b * 8 + mt], __ATOMIC_RELAXED, __HIP_MEMORY_SCOPE_AGENT) < mt + 1)
            __builtin_amdgcn_s_sleep(8);
    }
    __syncthreads();
    __builtin_amdgcn_fence(__ATOMIC_ACQUIRE, "agent");   // invalidate stale L2 lines
    __builtin_amdgcn_sched_barrier(0);

    int lane = tid & 63, wv = tid >> 6;
    int wr = wv >> 2, wc = wv & 3;
    int lrow = lane & 15, quad = lane >> 4;
    int sw = lrow & 7;

    const u16* Ab = P  + (long)b * 2048 * 2048 + (long)mt * 256 * 2048;  // lda 2048
    const u16* Bb = Vt + (long)nt * 256 * 16384 + b * 2048;              // ldb 16384
    float* Ob = O + (long)b * 2048 * 1024;
    const float* ls = lsum + b * 2048;

    int iters = (mt + 1) * 2;
    int tmax  = (mt + 1) * 4 - 1;

    floatx4 acc[8][4] = {};
    const int arow = (wr * 128 + lrow) * 64;
    const int brow = (wc * 64 + lrow) * 64;
    const int sl0 = (quad ^ sw) * 8;
    const int sl1 = ((4 + quad) ^ sw) * 8;

    EIGHT_PHASE_LOOP(Ab, Bb, 2048, 16384, iters, tmax)

    int crow0 = mt * 256 + wr * 128 + quad * 4;
    int ccol0 = nt * 256 + wc * 64 + lrow;
#pragma unroll
    for (int mi = 0; mi < 8; ++mi) {
#pragma unroll
        for (int r = 0; r < 4; ++r) {
            int row = crow0 + mi * 16 + r;
            float linv = 1.0f / ls[row];
#pragma unroll
            for (int ni = 0; ni < 4; ++ni)
                Ob[(long)row * 1024 + ccol0 + ni * 16] = acc[mi][ni][r] * linv;
        }
    }
}

// S-pool enumeration for rows 0..6, DESCENDING mt (row-6 first, row-0 last):
// cum counts: mt6:0-55, mt5:56-103, mt4:104-143, mt3:144-175, mt2:176-199,
// mt1:200-215, mt0:216-223. Within group: b = l/(m+1), nt = l%(m+1).
__device__ __forceinline__ void s_decode(int idx, int& b, int& mt, int& nt) {
    int start = 0;
    for (int m = 6; m >= 0; --m) {
        int cnt = 8 * (m + 1);
        if (idx < start + cnt) {
            int l = idx - start;
            b = l / (m + 1);
            nt = l - b * (m + 1);
            mt = m;
            return;
        }
        start += cnt;
    }
    b = 0; mt = 0; nt = 0;
}

// ============================================================================
// Mega-kernel: cvt -> gridsync -> qkv x3 -> gridsync -> s (static) -> pv (flags)
// Static schedule (256 blocks):
//   A: bid 0..63  : s=(b,7,nt) [row-7, round 1]; pv = j<4 ? (b,7,j) : (b,6,j-4)
//   B: bid 64..95 : s=S[160+i], S[192+i] (2nd unit always rows<=2); pv=(i>>2,0,i&3)
//   C: bid 96..255: s=S[c]; pv: mt=1+c/32, b=(c%32)>>2, nt=c&3
// Phase wall = pv7 critical path = 1 s-round + T(K=2048) ~= 116.4 us.
// ============================================================================
__global__ void __launch_bounds__(512, 2) mega(
    const float* __restrict__ x, const float* __restrict__ Wq,
    const float* __restrict__ Wk, const float* __restrict__ Wv,
    u16* __restrict__ xb, u16* __restrict__ wb, u16* __restrict__ QKi,
    u16* __restrict__ Vt, u16* __restrict__ P, float* __restrict__ lsum,
    int* __restrict__ srow, float* __restrict__ out)
{
    __shared__ u16 As[2][256 * 64];
    __shared__ u16 Bs[2][256 * 64];
    cg::grid_group grid = cg::this_grid();
    int bid = blockIdx.x, tid = threadIdx.x;

    // ---- phase 0: fp32->bf16 (x, W) + zero lsum/srow ----
    {
        long base = (long)bid * 512 + tid;
        const float4* x4 = (const float4*)x;
        ushort4* xb4 = (ushort4*)xb;
#pragma unroll 4
        for (int it = 0; it < 32; ++it) {                  // 32*131072 = 4,194,304
            long u = base + (long)it * 131072;
            float4 f = x4[u];
            ushort4 o;
            o.x = f32_to_bf16(f.x); o.y = f32_to_bf16(f.y);
            o.z = f32_to_bf16(f.z); o.w = f32_to_bf16(f.w);
            xb4[u] = o;
        }
#pragma unroll
        for (int it = 0; it < 6; ++it) {                   // 6*131072 = 786,432
            long u = base + (long)it * 131072;
            int which = (int)(u >> 18);
            long off = u & 262143;
            const float4* src = (const float4*)(which == 0 ? Wq : (which == 1 ? Wk : Wv));
            float4 f = src[off];
            ushort4 o;
            o.x = f32_to_bf16(f.x); o.y = f32_to_bf16(f.y);
            o.z = f32_to_bf16(f.z); o.w = f32_to_bf16(f.w);
            ((ushort4*)wb)[u] = o;
        }
        if (bid < 8) ((float4*)lsum)[bid * 512 + tid] = float4{0.f, 0.f, 0.f, 0.f};
        if (bid == 8 && tid < 64) srow[tid] = 0;
    }
    grid.sync();

    // ---- phase 1: QKV, 3 tiles/block (mapping identical to R5 grid 768) ----
    for (int k = 0; k < 3; ++k) {
        int u = k * 256 + bid;
        int wg = (u & 7) * 96 + (u >> 3);
        int mt = wg / 12, nt = wg - mt * 12;
        qkv_unit(mt, nt, xb, wb, QKi, Vt, As, Bs, tid);
    }
    grid.sync();

    // ---- phases 2+3: s units then pv unit, per static schedule ----
    int sb[2], smt[2], snt[2], ns;
    int pb, pmt, pnt;
    if (bid < 64) {
        ns = 1; sb[0] = bid >> 3; smt[0] = 7; snt[0] = bid & 7;
        int j = bid & 7; pb = bid >> 3;
        if (j < 4) { pmt = 7; pnt = j; } else { pmt = 6; pnt = j - 4; }
    } else if (bid < 96) {
        int i = bid - 64; ns = 2;
        s_decode(160 + i, sb[0], smt[0], snt[0]);
        s_decode(192 + i, sb[1], smt[1], snt[1]);
        pb = i >> 2; pmt = 0; pnt = i & 3;
    } else {
        int c = bid - 96; ns = 1;
        s_decode(c, sb[0], smt[0], snt[0]);
        pmt = 1 + c / 32; int sub = c & 31; pb = sub >> 2; pnt = sub & 3;
    }

    for (int k = 0; k < ns; ++k)
        s_unit(sb[k], smt[k], snt[k], QKi, P, lsum, srow, As, Bs, tid);

    pv_unit(pb, pmt, pnt, P, Vt, out, lsum, srow, As, Bs, tid);
}

extern "C" void kernel_launch(void* const* d_in, const int* in_sizes, int n_in,
                              void* d_out, int out_size, void* d_ws, size_t ws_size,
                              hipStream_t stream)
{
    const int B = 8, N = 2048, D = 1024;
    const long MT = (long)B * N;          // 16384
    const long nX = MT * D;               // 16,777,216
    const long nW = (long)D * D;          // 1,048,576

    const float* x  = (const float*)d_in[0];
    const float* Wq = (const float*)d_in[1];
    const float* Wk = (const float*)d_in[2];
    const float* Wv = (const float*)d_in[3];
    float* out = (float*)d_out;

    // ws layout (u16 units):
    u16* wb   = (u16*)d_ws;        // [3072][1024] stacked Wq;Wk;Wv
    u16* xb   = wb + 3 * nW;       // [16384][1024] bf16 x
    u16* QKi  = xb + nX;           // [16384][2048] Q|K interleaved
    u16* Vt   = QKi + MT * 2048;   // [1024][16384] V transposed
    u16* P    = Vt + nX;           // [8][2048][2048] exp(scores), unnormalized
    float* lsum = (float*)(P + (long)B * N * N);  // [8][2048] row sums
    int* srow = (int*)(lsum + 16384);             // [64] s row-completion counters

    void* kargs[] = {
        (void*)&x, (void*)&Wq, (void*)&Wk, (void*)&Wv,
        (void*)&xb, (void*)&wb, (void*)&QKi, (void*)&Vt,
        (void*)&P, (void*)&lsum, (void*)&srow, (void*)&out
    };
    hipLaunchCooperativeKernel((void*)mega, dim3(256), dim3(512), kargs, 0, stream);
}